// Round 3
// baseline (1148.325 us; speedup 1.0000x reference)
//
#include <hip/hip_runtime.h>
#include <math.h>

#define D 512
#define K 14
#define EPS 1e-8f
#define NROWS 65536

// Output float offsets (reference tuple order, flattened)
#define O_SNN       0          // 16*4096
#define O_PHINA     65536      // 16*4096*13
#define O_SAN       917504     // 16*4096
#define O_SAA       983040     // 16*4096
#define O_PHIOTHER  1048576    // 16*4096*12
#define O_SAANORM   1835008    // 16*4096
#define O_PSEUDO    1900544    // 16*4096
#define O_SCORES    1966080    // 16*4096
#define O_TN        2031616    // 512

__device__ __forceinline__ float wave_sum(float v) {
    v += __shfl_xor(v, 1);
    v += __shfl_xor(v, 2);
    v += __shfl_xor(v, 4);
    v += __shfl_xor(v, 8);
    v += __shfl_xor(v, 16);
    v += __shfl_xor(v, 32);
    return v;
}
__device__ __forceinline__ float wave_min(float v) {
    v = fminf(v, __shfl_xor(v, 1));
    v = fminf(v, __shfl_xor(v, 2));
    v = fminf(v, __shfl_xor(v, 4));
    v = fminf(v, __shfl_xor(v, 8));
    v = fminf(v, __shfl_xor(v, 16));
    v = fminf(v, __shfl_xor(v, 32));
    return v;
}
__device__ __forceinline__ float wave_max(float v) {
    v = fmaxf(v, __shfl_xor(v, 1));
    v = fmaxf(v, __shfl_xor(v, 2));
    v = fmaxf(v, __shfl_xor(v, 4));
    v = fmaxf(v, __shfl_xor(v, 8));
    v = fmaxf(v, __shfl_xor(v, 16));
    v = fmaxf(v, __shfl_xor(v, 32));
    return v;
}

__device__ __forceinline__ int bitrev4(int x) {
    return ((x & 1) << 3) | ((x & 2) << 1) | ((x & 4) >> 1) | ((x & 8) >> 3);
}

// Dual transpose-reduction: two independent 16-accumulator reductions with
// interleaved shuffle chains (the two chains' cross-lane latencies overlap).
// Result: lane l (l<16) holds totals of value bitrev4(l) for A and B.
__device__ __forceinline__ void multi_reduce16x2(float (&a)[16], float (&b)[16],
                                                 int lane, float& ra, float& rb) {
#pragma unroll
    for (int s = 0; s < 4; s++) {
        const int half = 8 >> s;          // 8,4,2,1
        const bool sel = (lane >> s) & 1;
#pragma unroll
        for (int i = 0; i < half; i++) {
            float alo = a[i], ahi = a[i + half];
            float blo = b[i], bhi = b[i + half];
            float ax = sel ? alo : ahi;
            float bx = sel ? blo : bhi;
            float ay = __shfl_xor(ax, 1 << s);
            float by = __shfl_xor(bx, 1 << s);
            a[i] = sel ? (ahi + ay) : (alo + ay);
            b[i] = sel ? (bhi + by) : (blo + by);
        }
    }
    float va = a[0], vb = b[0];
    float ta = __shfl_xor(va, 16);
    float tb = __shfl_xor(vb, 16);
    va += ta; vb += tb;
    ta = __shfl_xor(va, 32);
    tb = __shfl_xor(vb, 32);
    ra = va + ta; rb = vb + tb;
}

// Kernel A: normalize T_emb rows 0..13 into W[0..13], copy w_score into W[14],
// and write T_n_enhanced. One wave per row -> 15 blocks.
__global__ __launch_bounds__(64) void kprep(const float* __restrict__ T_emb,
                                            const float* __restrict__ w_score,
                                            float* __restrict__ W,
                                            float* __restrict__ tn_out) {
    int lane = threadIdx.x;
    int w = blockIdx.x; // 0..14
    float4* W4 = (float4*)W;
    if (w < K) {
        const float4* src = (const float4*)T_emb + w * 128;
        float4 a = src[lane];
        float4 b = src[64 + lane];
        float ss = a.x * a.x + a.y * a.y + a.z * a.z + a.w * a.w
                 + b.x * b.x + b.y * b.y + b.z * b.z + b.w * b.w;
        ss = wave_sum(ss);
        float inv = 1.0f / (sqrtf(ss) + EPS);
        float4 na = make_float4(a.x * inv, a.y * inv, a.z * inv, a.w * inv);
        float4 nb = make_float4(b.x * inv, b.y * inv, b.z * inv, b.w * inv);
        W4[w * 128 + lane] = na;
        W4[w * 128 + 64 + lane] = nb;
        if (w == K - 1) {
            float4* t4 = (float4*)tn_out;
            t4[lane] = na;
            t4[64 + lane] = nb;
        }
    } else {
        const float4* src = (const float4*)w_score;
        W4[14 * 128 + lane] = src[lane];
        W4[14 * 128 + 64 + lane] = src[64 + lane];
    }
}

// Kernel B: streaming dot kernel, W in LDS, TWO rows per wave per iteration.
// Each W ds_read_b128 pair feeds 16 FMAs (2 rows) -> latency covered by the
// dependent-FMA window; per-row W traffic halves (15 reads vs 30).
// Grid 1280 = exactly 5 blocks/CU (LDS cap at ~30KB); launch_bounds(256,5)
// caps VGPR ~102 (estimated use ~85, leaving pipelining headroom).
template <bool ANOM>
__global__ __launch_bounds__(256, 5) void kdot(const float4* __restrict__ feats,
                                               const float4* __restrict__ W4,
                                               const int* __restrict__ cls,
                                               const float* __restrict__ b_score,
                                               float* __restrict__ S_nn,
                                               float* __restrict__ phi_na,
                                               float* __restrict__ S_an,
                                               float* __restrict__ S_aa,
                                               float* __restrict__ phi_other,
                                               float* __restrict__ scores) {
    constexpr int NK = ANOM ? 15 : 14;
    __shared__ float4 Wl[NK * 128];   // 30.7 / 28.7 KB

    for (int i = threadIdx.x; i < NK * 128; i += 256) Wl[i] = W4[i];
    __syncthreads();

    int lane = threadIdx.x & 63;
    int wave = (blockIdx.x << 2) + (threadIdx.x >> 6);
    int nw = (int)(gridDim.x << 2);
    const int myk = bitrev4(lane);
    float bsc = ANOM ? *b_score : 0.0f;

    const int NPAIRS = NROWS / 2;
    int p = wave;
    const float4* fp = feats + (size_t)p * 256; // pair = 2 rows = 256 float4
    float4 fA0 = fp[lane];
    float4 fA1 = fp[64 + lane];
    float4 fB0 = fp[128 + lane];
    float4 fB1 = fp[192 + lane];

    while (p < NPAIRS) {
        int np = p + nw;
        float4 gA0, gA1, gB0, gB1;
        if (np < NPAIRS) {
            const float4* gp = feats + (size_t)np * 256;
            gA0 = gp[lane];
            gA1 = gp[64 + lane];
            gB0 = gp[128 + lane];
            gB1 = gp[192 + lane];
        }

        float valsA[16], valsB[16];
#pragma unroll
        for (int k = 0; k < NK; k++) {
            float4 w0 = Wl[k * 128 + lane];
            float4 w1 = Wl[k * 128 + 64 + lane];
            float sa = fA0.x * w0.x;
            sa = fmaf(fA0.y, w0.y, sa);
            sa = fmaf(fA0.z, w0.z, sa);
            sa = fmaf(fA0.w, w0.w, sa);
            sa = fmaf(fA1.x, w1.x, sa);
            sa = fmaf(fA1.y, w1.y, sa);
            sa = fmaf(fA1.z, w1.z, sa);
            sa = fmaf(fA1.w, w1.w, sa);
            valsA[k] = sa;
            float sb = fB0.x * w0.x;
            sb = fmaf(fB0.y, w0.y, sb);
            sb = fmaf(fB0.z, w0.z, sb);
            sb = fmaf(fB0.w, w0.w, sb);
            sb = fmaf(fB1.x, w1.x, sb);
            sb = fmaf(fB1.y, w1.y, sb);
            sb = fmaf(fB1.z, w1.z, sb);
            sb = fmaf(fB1.w, w1.w, sb);
            valsB[k] = sb;
        }
#pragma unroll
        for (int k = NK; k < 16; k++) { valsA[k] = 0.0f; valsB[k] = 0.0f; }

        float vA, vB;
        multi_reduce16x2(valsA, valsB, lane, vA, vB);

        int rowA = 2 * p;
        int rowB = rowA + 1;
        if (ANOM) {
            if (lane < 16 && myk < 15) {
                int ci = cls[rowA >> 12]; // wave-uniform; rowB same batch
                float valA = vA, valB = vB;
                float *ptrA, *ptrB;
                if (myk < 13) {
                    int ok = (myk < ci) ? myk : myk - 1;
                    ptrA = (myk == ci) ? (S_aa + rowA) : (phi_other + rowA * 12 + ok);
                    ptrB = (myk == ci) ? (S_aa + rowB) : (phi_other + rowB * 12 + ok);
                } else if (myk == 13) {
                    ptrA = S_an + rowA;
                    ptrB = S_an + rowB;
                } else {
                    ptrA = scores + rowA;
                    ptrB = scores + rowB;
                    valA = 1.0f / (1.0f + expf(-(vA + bsc)));
                    valB = 1.0f / (1.0f + expf(-(vB + bsc)));
                }
                *ptrA = valA;
                *ptrB = valB;
            }
        } else {
            if (lane < 16 && myk < 14) {
                float* ptrA = (myk < 13) ? (phi_na + rowA * 13 + myk) : (S_nn + rowA);
                float* ptrB = (myk < 13) ? (phi_na + rowB * 13 + myk) : (S_nn + rowB);
                *ptrA = vA;
                *ptrB = vB;
            }
        }
        p = np;
        fA0 = gA0; fA1 = gA1; fB0 = gB0; fB1 = gB1;
    }
}

// Kernel C: per-batch min/max + normalize + fuse, one block per batch.
// All 32 values stay in registers across the reduction (no second read pass).
__global__ __launch_bounds__(256) void kpost(const float* __restrict__ S_aa,
                                             const float* __restrict__ S_an,
                                             float* __restrict__ S_aa_norm,
                                             float* __restrict__ pseudo) {
    int b = blockIdx.x;
    int t = threadIdx.x;
    int lane = t & 63, wid = t >> 6;
    const float* pa = S_aa + b * 4096;
    const float* pn = S_an + b * 4096;
    float a[16], n[16];
    float mnA = 1e30f, mxA = -1e30f, mnN = 1e30f, mxN = -1e30f;
#pragma unroll
    for (int i = 0; i < 16; i++) {
        a[i] = pa[t + i * 256];
        n[i] = pn[t + i * 256];
        mnA = fminf(mnA, a[i]); mxA = fmaxf(mxA, a[i]);
        mnN = fminf(mnN, n[i]); mxN = fmaxf(mxN, n[i]);
    }
    mnA = wave_min(mnA); mxA = wave_max(mxA);
    mnN = wave_min(mnN); mxN = wave_max(mxN);
    __shared__ float red[4][4];
    if (lane == 0) {
        red[wid][0] = mnA; red[wid][1] = mxA;
        red[wid][2] = mnN; red[wid][3] = mxN;
    }
    __syncthreads();
    mnA = fminf(fminf(red[0][0], red[1][0]), fminf(red[2][0], red[3][0]));
    mxA = fmaxf(fmaxf(red[0][1], red[1][1]), fmaxf(red[2][1], red[3][1]));
    mnN = fminf(fminf(red[0][2], red[1][2]), fminf(red[2][2], red[3][2]));
    mxN = fmaxf(fmaxf(red[0][3], red[1][3]), fmaxf(red[2][3], red[3][3]));
    float dA = mxA - mnA + EPS;
    float dN = mxN - mnN + EPS;
#pragma unroll
    for (int i = 0; i < 16; i++) {
        float s_aa = (a[i] - mnA) / dA;
        float s_an = (n[i] - mnN) / dN;
        float fused = 0.8f * s_aa + 0.2f * (1.0f - s_an);
        pseudo[b * 4096 + t + i * 256] = fused > 0.55f ? 1.0f : 0.0f;
        S_aa_norm[b * 4096 + t + i * 256] = s_aa;
    }
}

extern "C" void kernel_launch(void* const* d_in, const int* in_sizes, int n_in,
                              void* d_out, int out_size, void* d_ws, size_t ws_size,
                              hipStream_t stream) {
    const float* normal_feats  = (const float*)d_in[0];
    const float* anomaly_feats = (const float*)d_in[1];
    const int*   cls           = (const int*)d_in[2];
    const float* T_emb         = (const float*)d_in[3];
    const float* w_score       = (const float*)d_in[4];
    const float* b_score       = (const float*)d_in[5];
    float* out = (float*)d_out;

    float* W = (float*)d_ws; // 15*512 floats

    kprep<<<15, 64, 0, stream>>>(T_emb, w_score, W, out + O_TN);

    // Sequential 128 MB streams; grid 1280 = exactly 5 blocks/CU (LDS cap).
    kdot<false><<<1280, 256, 0, stream>>>((const float4*)normal_feats,
                                          (const float4*)W, nullptr, b_score,
                                          out + O_SNN, out + O_PHINA,
                                          nullptr, nullptr, nullptr, nullptr);

    kdot<true><<<1280, 256, 0, stream>>>((const float4*)anomaly_feats,
                                         (const float4*)W, cls, b_score,
                                         nullptr, nullptr,
                                         out + O_SAN, out + O_SAA,
                                         out + O_PHIOTHER, out + O_SCORES);

    kpost<<<16, 256, 0, stream>>>(out + O_SAA, out + O_SAN,
                                  out + O_SAANORM, out + O_PSEUDO);
}

// Round 4
// 310.499 us; speedup vs baseline: 3.6983x; 3.6983x over previous
//
#include <hip/hip_runtime.h>
#include <math.h>

#define D 512
#define K 14
#define EPS 1e-8f
#define NROWS 65536

// Output float offsets (reference tuple order, flattened)
#define O_SNN       0          // 16*4096
#define O_PHINA     65536      // 16*4096*13
#define O_SAN       917504     // 16*4096
#define O_SAA       983040     // 16*4096
#define O_PHIOTHER  1048576    // 16*4096*12
#define O_SAANORM   1835008    // 16*4096
#define O_PSEUDO    1900544    // 16*4096
#define O_SCORES    1966080    // 16*4096
#define O_TN        2031616    // 512

__device__ __forceinline__ float wave_sum(float v) {
    v += __shfl_xor(v, 1);
    v += __shfl_xor(v, 2);
    v += __shfl_xor(v, 4);
    v += __shfl_xor(v, 8);
    v += __shfl_xor(v, 16);
    v += __shfl_xor(v, 32);
    return v;
}
__device__ __forceinline__ float wave_min(float v) {
    v = fminf(v, __shfl_xor(v, 1));
    v = fminf(v, __shfl_xor(v, 2));
    v = fminf(v, __shfl_xor(v, 4));
    v = fminf(v, __shfl_xor(v, 8));
    v = fminf(v, __shfl_xor(v, 16));
    v = fminf(v, __shfl_xor(v, 32));
    return v;
}
__device__ __forceinline__ float wave_max(float v) {
    v = fmaxf(v, __shfl_xor(v, 1));
    v = fmaxf(v, __shfl_xor(v, 2));
    v = fmaxf(v, __shfl_xor(v, 4));
    v = fmaxf(v, __shfl_xor(v, 8));
    v = fmaxf(v, __shfl_xor(v, 16));
    v = fmaxf(v, __shfl_xor(v, 32));
    return v;
}

// 8-value transpose-reduction: 8 per-lane accumulators -> full 64-lane sums.
// Result: lane l (l<8) holds the total of value bitrev3(l). 10 shuffles.
__device__ __forceinline__ float multi_reduce8(float (&vals)[8], int lane) {
#pragma unroll
    for (int s = 0; s < 3; s++) {
        const int half = 4 >> s;          // 4,2,1
        const bool sel = (lane >> s) & 1;
#pragma unroll
        for (int i = 0; i < half; i++) {
            float lo = vals[i], hi = vals[i + half];
            float a = sel ? lo : hi;
            float b = __shfl_xor(a, 1 << s);
            vals[i] = sel ? (hi + b) : (lo + b);
        }
    }
    float v = vals[0];
    v += __shfl_xor(v, 8);
    v += __shfl_xor(v, 16);
    v += __shfl_xor(v, 32);
    return v;
}

__device__ __forceinline__ int bitrev3(int x) {
    return ((x & 1) << 2) | (x & 2) | ((x & 4) >> 2);
}

// Kernel A: normalize T_emb rows 0..13 into W[0..13], w_score into W[14],
// zeros into W[15] (dead k-slot for the odd k-group), T_n_enhanced to output.
__global__ __launch_bounds__(64) void kprep(const float* __restrict__ T_emb,
                                            const float* __restrict__ w_score,
                                            float* __restrict__ W,
                                            float* __restrict__ tn_out) {
    int lane = threadIdx.x;
    int w = blockIdx.x; // 0..15
    float4* W4 = (float4*)W;
    if (w < K) {
        const float4* src = (const float4*)T_emb + w * 128;
        float4 a = src[lane];
        float4 b = src[64 + lane];
        float ss = a.x * a.x + a.y * a.y + a.z * a.z + a.w * a.w
                 + b.x * b.x + b.y * b.y + b.z * b.z + b.w * b.w;
        ss = wave_sum(ss);
        float inv = 1.0f / (sqrtf(ss) + EPS);
        float4 na = make_float4(a.x * inv, a.y * inv, a.z * inv, a.w * inv);
        float4 nb = make_float4(b.x * inv, b.y * inv, b.z * inv, b.w * inv);
        W4[w * 128 + lane] = na;
        W4[w * 128 + 64 + lane] = nb;
        if (w == K - 1) {
            float4* t4 = (float4*)tn_out;
            t4[lane] = na;
            t4[64 + lane] = nb;
        }
    } else if (w == 14) {
        const float4* src = (const float4*)w_score;
        W4[14 * 128 + lane] = src[lane];
        W4[14 * 128 + 64 + lane] = src[64 + lane];
    } else {
        float4 z = make_float4(0.f, 0.f, 0.f, 0.f);
        W4[15 * 128 + lane] = z;
        W4[15 * 128 + 64 + lane] = z;
    }
}

// Kernel B: streaming dot kernel, K SPLIT ACROSS WAVE PAIRS to kill spilling.
// Even waves own k 0..7, odd waves k 8..15 (row 15 is zeros, result discarded).
// W fragment = 8 x 2 float4 = 64 VGPR; total live state ~100 VGPR -> no
// scratch, actual occupancy 4 waves/SIMD. Pair waves (2w, 2w+1) sit in the
// same block and stream the SAME rows, so the duplicate global reads are
// L1/L2 hits on the same CU: HBM fetch stays ~134 MB.
template <bool ANOM>
__global__ __launch_bounds__(256, 2) void kdot(const float4* __restrict__ feats,
                                               const float4* __restrict__ W4,
                                               const int* __restrict__ cls,
                                               const float* __restrict__ b_score,
                                               float* __restrict__ S_nn,
                                               float* __restrict__ phi_na,
                                               float* __restrict__ S_an,
                                               float* __restrict__ S_aa,
                                               float* __restrict__ phi_other,
                                               float* __restrict__ scores) {
    int lane = threadIdx.x & 63;
    int wid = threadIdx.x >> 6;           // 0..3
    int kbase = (wid & 1) * 8;

    float4 t0[8], t1[8];
#pragma unroll
    for (int j = 0; j < 8; j++) {
        t0[j] = W4[(kbase + j) * 128 + lane];
        t1[j] = W4[(kbase + j) * 128 + 64 + lane];
    }
    const int myk = kbase + bitrev3(lane & 7);
    float bsc = ANOM ? *b_score : 0.0f;

    int pair = blockIdx.x * 2 + (wid >> 1);
    int npairs = (int)gridDim.x * 2;      // 2048 -> 32 rows per pair

    int row = pair;
    float4 f0 = feats[(size_t)row * 128 + lane];
    float4 f1 = feats[(size_t)row * 128 + 64 + lane];
    while (row < NROWS) {
        int nrow = row + npairs;
        float4 g0, g1;
        if (nrow < NROWS) {
            g0 = feats[(size_t)nrow * 128 + lane];
            g1 = feats[(size_t)nrow * 128 + 64 + lane];
        }
        float vals[8];
#pragma unroll
        for (int j = 0; j < 8; j++) {
            float s = f0.x * t0[j].x;
            s = fmaf(f0.y, t0[j].y, s);
            s = fmaf(f0.z, t0[j].z, s);
            s = fmaf(f0.w, t0[j].w, s);
            s = fmaf(f1.x, t1[j].x, s);
            s = fmaf(f1.y, t1[j].y, s);
            s = fmaf(f1.z, t1[j].z, s);
            s = fmaf(f1.w, t1[j].w, s);
            vals[j] = s;
        }
        float v = multi_reduce8(vals, lane);

        if (lane < 8) {
            if (ANOM) {
                if (myk < 15) {
                    int ci = cls[row >> 12]; // wave-uniform, L1-hot
                    float val = v;
                    float* ptr;
                    if (myk < 13) {
                        ptr = (myk == ci) ? (S_aa + row)
                                          : (phi_other + row * 12 + ((myk < ci) ? myk : myk - 1));
                    } else if (myk == 13) {
                        ptr = S_an + row;
                    } else {
                        ptr = scores + row;
                        val = 1.0f / (1.0f + expf(-(v + bsc)));
                    }
                    *ptr = val;
                }
            } else {
                if (myk < 14) {
                    float* ptr = (myk < 13) ? (phi_na + row * 13 + myk) : (S_nn + row);
                    *ptr = v;
                }
            }
        }
        row = nrow; f0 = g0; f1 = g1;
    }
}

// Kernel C: per-batch min/max + normalize + fuse, one block per batch.
__global__ __launch_bounds__(256) void kpost(const float* __restrict__ S_aa,
                                             const float* __restrict__ S_an,
                                             float* __restrict__ S_aa_norm,
                                             float* __restrict__ pseudo) {
    int b = blockIdx.x;
    int t = threadIdx.x;
    int lane = t & 63, wid = t >> 6;
    const float* pa = S_aa + b * 4096;
    const float* pn = S_an + b * 4096;
    float a[16], n[16];
    float mnA = 1e30f, mxA = -1e30f, mnN = 1e30f, mxN = -1e30f;
#pragma unroll
    for (int i = 0; i < 16; i++) {
        a[i] = pa[t + i * 256];
        n[i] = pn[t + i * 256];
        mnA = fminf(mnA, a[i]); mxA = fmaxf(mxA, a[i]);
        mnN = fminf(mnN, n[i]); mxN = fmaxf(mxN, n[i]);
    }
    mnA = wave_min(mnA); mxA = wave_max(mxA);
    mnN = wave_min(mnN); mxN = wave_max(mxN);
    __shared__ float red[4][4];
    if (lane == 0) {
        red[wid][0] = mnA; red[wid][1] = mxA;
        red[wid][2] = mnN; red[wid][3] = mxN;
    }
    __syncthreads();
    mnA = fminf(fminf(red[0][0], red[1][0]), fminf(red[2][0], red[3][0]));
    mxA = fmaxf(fmaxf(red[0][1], red[1][1]), fmaxf(red[2][1], red[3][1]));
    mnN = fminf(fminf(red[0][2], red[1][2]), fminf(red[2][2], red[3][2]));
    mxN = fmaxf(fmaxf(red[0][3], red[1][3]), fmaxf(red[2][3], red[3][3]));
    float dA = mxA - mnA + EPS;
    float dN = mxN - mnN + EPS;
#pragma unroll
    for (int i = 0; i < 16; i++) {
        float s_aa = (a[i] - mnA) / dA;
        float s_an = (n[i] - mnN) / dN;
        float fused = 0.8f * s_aa + 0.2f * (1.0f - s_an);
        pseudo[b * 4096 + t + i * 256] = fused > 0.55f ? 1.0f : 0.0f;
        S_aa_norm[b * 4096 + t + i * 256] = s_aa;
    }
}

extern "C" void kernel_launch(void* const* d_in, const int* in_sizes, int n_in,
                              void* d_out, int out_size, void* d_ws, size_t ws_size,
                              hipStream_t stream) {
    const float* normal_feats  = (const float*)d_in[0];
    const float* anomaly_feats = (const float*)d_in[1];
    const int*   cls           = (const int*)d_in[2];
    const float* T_emb         = (const float*)d_in[3];
    const float* w_score       = (const float*)d_in[4];
    const float* b_score       = (const float*)d_in[5];
    float* out = (float*)d_out;

    float* W = (float*)d_ws; // 16*512 floats (row 15 = zeros)

    kprep<<<16, 64, 0, stream>>>(T_emb, w_score, W, out + O_TN);

    // Sequential 128 MB streams; 1024 blocks -> 4 blocks/CU at <=128 VGPR.
    kdot<false><<<1024, 256, 0, stream>>>((const float4*)normal_feats,
                                          (const float4*)W, nullptr, b_score,
                                          out + O_SNN, out + O_PHINA,
                                          nullptr, nullptr, nullptr, nullptr);

    kdot<true><<<1024, 256, 0, stream>>>((const float4*)anomaly_feats,
                                         (const float4*)W, cls, b_score,
                                         nullptr, nullptr,
                                         out + O_SAN, out + O_SAA,
                                         out + O_PHIOTHER, out + O_SCORES);

    kpost<<<16, 256, 0, stream>>>(out + O_SAA, out + O_SAN,
                                  out + O_SAANORM, out + O_PSEUDO);
}